// Round 3
// baseline (70.793 us; speedup 1.0000x reference)
//
#include <hip/hip_runtime.h>
#include <hip/hip_bf16.h>

typedef __attribute__((ext_vector_type(8))) short bf16x8;
typedef __attribute__((ext_vector_type(4))) float f32x4;

constexpr int BQ  = 4096;          // batch per view
constexpr int DD  = 128;           // dim
constexpr int N2  = 2 * BQ;        // 8192
constexpr int NT  = 64;            // number of 128-row tiles
constexpr int NPAIR = NT * (NT + 1) / 2;   // 2080 upper-triangle tile pairs
// exp(s/T) = exp2(s * 2/ln2); pre-scale matrix by sqrt(2.8853900817779268)
constexpr float SQS = 1.6986433f;

static __device__ __forceinline__ ushort f2bf(float f) {
    unsigned u = __builtin_bit_cast(unsigned, f);
    u += 0x7FFFu + ((u >> 16) & 1u);     // round-to-nearest-even
    return (ushort)(u >> 16);
}

// ---- kernel 1: fp32 -> bf16 in MFMA-fragment order, plus mask keys --------
// obF layout: frag(group,kk) at index (group*4+kk)*64+lane, 8 bf16 per lane:
// a fragment load is F[base+lane] -> one fully contiguous 1KB load per wave.
__global__ __launch_bounds__(256) void convert_k(const float* __restrict__ a,
        const float* __restrict__ b, const int* __restrict__ tgt,
        ushort* __restrict__ obF, int* __restrict__ key)
{
    int t = blockIdx.x * 256 + threadIdx.x;          // 131072 threads
    int row = t >> 4, c8 = t & 15;
    const float* src = (row < BQ) ? (a + (size_t)row * DD + c8 * 8)
                                  : (b + (size_t)(row - BQ) * DD + c8 * 8);
    float4 v0 = reinterpret_cast<const float4*>(src)[0];
    float4 v1 = reinterpret_cast<const float4*>(src)[1];
    bf16x8 res;
    res[0] = (short)f2bf(v0.x * SQS); res[1] = (short)f2bf(v0.y * SQS);
    res[2] = (short)f2bf(v0.z * SQS); res[3] = (short)f2bf(v0.w * SQS);
    res[4] = (short)f2bf(v1.x * SQS); res[5] = (short)f2bf(v1.y * SQS);
    res[6] = (short)f2bf(v1.z * SQS); res[7] = (short)f2bf(v1.w * SQS);
    int frag = ((row >> 4) * 4 + (c8 >> 2)) * 64 + (c8 & 3) * 16 + (row & 15);
    *reinterpret_cast<bf16x8*>(obF + (size_t)frag * 8) = res;

    if (t < N2) {
        // excl(i,j) == (key[i]==key[j]) covers BOTH the pair mask and the
        // target mask (rowmod==colmod implies identical target).
        int tv = tgt[t & (BQ - 1)];
        key[t] = (tv == -1) ? (0x40000000 + (t & (BQ - 1))) : tv;
    }
}

// ---- kernel 2: symmetric fused Gram + exp + mask + row/col sums ------------
// One block per tile pair (i<=j) of 128x128; 512 thr = 8 waves (4wr x 2wc),
// wave tile 32x64. A frags in registers; B panel (32KB) staged once in LDS.
__global__ __launch_bounds__(512, 4) void simloss_main(
        const ushort* __restrict__ obF, const int* __restrict__ key,
        float* __restrict__ pf, float* __restrict__ png)
{
    __shared__ ushort bpan[16384];       // 32KB B panel (fragment-ordered)
    __shared__ float rred[2][128][2];    // row partials across wc
    __shared__ float cred[4][128][2];    // col partials across wr

    const int tid  = threadIdx.x;
    const int lane = tid & 63;
    const int wid  = tid >> 6;
    const int wr   = wid >> 1;           // 0..3
    const int wc   = wid & 1;            // 0..1
    const int l15  = lane & 15;
    const int l4   = lane >> 4;

    // XCD-bijective swizzle (2080 % 8 == 0), then triangular (i,j) mapping
    int raw = blockIdx.x;
    int bid = (raw & 7) * (NPAIR / 8) + (raw >> 3);
    int i = (int)(64.5f - sqrtf(4160.25f - 2.0f * (float)bid));
    while (i * NT - i * (i - 1) / 2 > bid) --i;
    while ((i + 1) * NT - (i + 1) * i / 2 <= bid) ++i;
    const int j = i + (bid - (i * NT - i * (i - 1) / 2));

    // stage B panel: 32KB contiguous (col tile j = frag groups j*8..j*8+7)
    {
        const ushort* src = obF + (size_t)j * 16384;
        for (int s = 0; s < 4; ++s) {
            unsigned loff = (unsigned)__builtin_amdgcn_readfirstlane(s * 8192 + wid * 1024);
            const ushort* g = src + s * 4096 + wid * 512 + lane * 8;
            ushort* l = (ushort*)((char*)bpan + loff);
            __builtin_amdgcn_global_load_lds(
                (const __attribute__((address_space(1))) void*)g,
                (__attribute__((address_space(3))) void*)l, 16, 0, 0);
        }
    }

    // A fragments (rows i*128 + wr*32 .. +32), hoisted for the whole block
    const bf16x8* F = reinterpret_cast<const bf16x8*>(obF);
    const int ga = i * 8 + wr * 2;
    bf16x8 af[2][4];
#pragma unroll
    for (int m = 0; m < 2; ++m)
#pragma unroll
        for (int kk = 0; kk < 4; ++kk)
            af[m][kk] = F[((ga + m) * 4 + kk) * 64 + lane];

    int rk[2][4];
#pragma unroll
    for (int m = 0; m < 2; ++m)
#pragma unroll
        for (int r = 0; r < 4; ++r)
            rk[m][r] = key[i * 128 + wr * 32 + m * 16 + l4 * 4 + r];
    int ck[4];
#pragma unroll
    for (int n = 0; n < 4; ++n)
        ck[n] = key[j * 128 + wc * 64 + n * 16 + l15];

    __syncthreads();   // drains vmcnt -> B panel visible to all waves

    // MFMA: 32 x 16x16x32 per wave
    const bf16x8* BL = reinterpret_cast<const bf16x8*>(bpan);
    f32x4 acc[2][4] = {};
#pragma unroll
    for (int kk = 0; kk < 4; ++kk) {
        bf16x8 bf[4];
#pragma unroll
        for (int n = 0; n < 4; ++n)
            bf[n] = BL[((wc * 4 + n) * 4 + kk) * 64 + lane];
#pragma unroll
        for (int m = 0; m < 2; ++m)
#pragma unroll
            for (int n = 0; n < 4; ++n)
                acc[m][n] = __builtin_amdgcn_mfma_f32_16x16x32_bf16(
                    af[m][kk], bf[n], acc[m][n], 0, 0, 0);
    }

    // epilogue: exp + mask; accumulate row partials AND col partials
    float fs[2][4] = {}, ns[2][4] = {}, cs[4] = {}, ms[4] = {};
#pragma unroll
    for (int m = 0; m < 2; ++m)
#pragma unroll
        for (int n = 0; n < 4; ++n)
#pragma unroll
            for (int r = 0; r < 4; ++r) {
                float e = __builtin_amdgcn_exp2f(acc[m][n][r]);
                float sel = (rk[m][r] == ck[n]) ? 0.0f : e;
                fs[m][r] += e;   ns[m][r] += sel;
                cs[n]    += e;   ms[n]    += sel;
            }

    // row reduce across 16 col-lanes -> rred[wc][row_local]
#pragma unroll
    for (int m = 0; m < 2; ++m)
#pragma unroll
        for (int r = 0; r < 4; ++r) {
            float f = fs[m][r], g = ns[m][r];
#pragma unroll
            for (int msk = 1; msk < 16; msk <<= 1) {
                f += __shfl_xor(f, msk);
                g += __shfl_xor(g, msk);
            }
            if (l15 == 0) {
                int rl = wr * 32 + m * 16 + l4 * 4 + r;
                rred[wc][rl][0] = f;
                rred[wc][rl][1] = g;
            }
        }
    // col reduce across the 4 l4 groups -> cred[wr][col_local]
    if (i != j) {
#pragma unroll
        for (int n = 0; n < 4; ++n) {
            float f = cs[n], g = ms[n];
            f += __shfl_xor(f, 16); g += __shfl_xor(g, 16);
            f += __shfl_xor(f, 32); g += __shfl_xor(g, 32);
            if (l4 == 0) {
                int cl = wc * 64 + n * 16 + l15;
                cred[wr][cl][0] = f;
                cred[wr][cl][1] = g;
            }
        }
    }
    __syncthreads();

    // final writes: slot j gets tile-i rows; slot i gets tile-j rows (cols)
    if (tid < 128) {
        float f = rred[0][tid][0] + rred[1][tid][0];
        float g = rred[0][tid][1] + rred[1][tid][1];
        pf [j * N2 + i * 128 + tid] = f;
        png[j * N2 + i * 128 + tid] = g;
    } else if (tid < 256 && i != j) {
        int cl = tid - 128;
        float f = cred[0][cl][0] + cred[1][cl][0] + cred[2][cl][0] + cred[3][cl][0];
        float g = cred[0][cl][1] + cred[1][cl][1] + cred[2][cl][1] + cred[3][cl][1];
        pf [i * N2 + j * 128 + cl] = f;
        png[i * N2 + j * 128 + cl] = g;
    }
}

// ---- kernel 3: per-row loss + block partial -------------------------------
__global__ __launch_bounds__(256) void row_loss_k(
        const float* __restrict__ pf, const float* __restrict__ png,
        float* __restrict__ bpart)
{
    int row = blockIdx.x * 256 + threadIdx.x;
    float full = 0.f, ng = 0.f;
#pragma unroll
    for (int s = 0; s < NT; ++s) {
        full += pf[s * N2 + row];
        ng   += png[s * N2 + row];
    }
    float o1 = full - 0.9f * ng;                // (1 - tau+) = 0.9
    float o2 = full + 818.1f * ng;              // n*tau+ - (1-tau+) = 819 - 0.9
    float li = (__builtin_amdgcn_logf(o2) - __builtin_amdgcn_logf(o1)) * 0.6931471805599453f;

#pragma unroll
    for (int m = 1; m < 64; m <<= 1) li += __shfl_xor(li, m);
    __shared__ float red[4];
    if ((threadIdx.x & 63) == 0) red[threadIdx.x >> 6] = li;
    __syncthreads();
    if (threadIdx.x == 0) bpart[blockIdx.x] = red[0] + red[1] + red[2] + red[3];
}

// ---- kernel 4: final scalar ----------------------------------------------
__global__ void final_k(const float* __restrict__ bpart, float* __restrict__ out)
{
    int l = threadIdx.x;
    float v = (l < 32) ? bpart[l] : 0.f;
#pragma unroll
    for (int m = 1; m < 32; m <<= 1) v += __shfl_xor(v, m);
    if (l == 0) out[0] = v / (float)N2;
}

extern "C" void kernel_launch(void* const* d_in, const int* in_sizes, int n_in,
                              void* d_out, int out_size, void* d_ws, size_t ws_size,
                              hipStream_t stream)
{
    const float* out1 = (const float*)d_in[0];
    const float* out2 = (const float*)d_in[1];
    // d_in[2] = out_m, unused by the loss math
    const int*   tgt  = (const int*)d_in[3];
    float* out = (float*)d_out;

    // ws: obF 2MB | pf 2MB | png 2MB | key 32KB | bpart 128B
    ushort* obF  = (ushort*)d_ws;
    float*  pf   = (float*)((char*)d_ws + (2u << 20));
    float*  png  = (float*)((char*)d_ws + (4u << 20));
    int*    key  = (int*)  ((char*)d_ws + (6u << 20));
    float*  bpart= (float*)((char*)d_ws + (6u << 20) + N2 * 4);

    convert_k<<<(N2 * DD / 8) / 256, 256, 0, stream>>>(out1, out2, tgt, obF, key);
    simloss_main<<<NPAIR, 512, 0, stream>>>(obF, key, pf, png);
    row_loss_k<<<N2 / 256, 256, 0, stream>>>(pf, png, bpart);
    final_k<<<1, 64, 0, stream>>>(bpart, out);
}